// Round 12
// baseline (321.248 us; speedup 1.0000x reference)
//
#include <hip/hip_runtime.h>
#include <math.h>

#define NCL 10
#define DM 512
#define NH 8
#define DK 64
#define NB 8
#define SL 2048
#define LK 228
#define UF 100
#define KP_PER_B (NH*LK*DK)     // 116736
#define KP_TOT (NB*KP_PER_B)    // 933888
#define NROWS (NB*LK*UF)        // 182400
#define POOL2_BLOCKS 8192       // 2*NB*DM channels, one per block
#define KCCS_BLOCKS 3648        // KP_TOT/256
#define KCE_BLOCKS 200          // 800 (b,u) units, 4 per block

typedef __bf16 bf16_t;
typedef __attribute__((ext_vector_type(2))) __bf16 bf16x2;
typedef __attribute__((ext_vector_type(4))) __bf16 bf16x4;
typedef __attribute__((ext_vector_type(8))) __bf16 bf16x8;
typedef __attribute__((ext_vector_type(4))) float f32x4;

__device__ __forceinline__ float gelu_f(float x) {
    return 0.5f * x * (1.f + erff(x * 0.70710678118654752f));
}

// ------------- kernel 1: max-pool K,V, LDS-staged coalesced ------------------
// One block per (kv, b, c) channel; stage 2048-float row via float4, max from
// LDS (stride 9 coprime to 32 banks -> conflict-free). K path writes f32 Kp
// (mlp needs f32); V path writes bf16 Vp (attn rounds to bf16 anyway ->
// bit-identical, half the bytes). Tail: W1 bf16 prep + acc init.
__global__ void k_pool(const float* __restrict__ K, const float* __restrict__ V,
                       float* __restrict__ Kp, bf16_t* __restrict__ Vpb,
                       const float* __restrict__ Wq1, bf16_t* __restrict__ W1b,
                       float* __restrict__ acc) {
    int bid = blockIdx.x;
    int tid = threadIdx.x;
    if (bid >= POOL2_BLOCKS) {
        int i = (bid - POOL2_BLOCKS) * 256 + tid;
        if (i < 512 * 40) W1b[i] = (bf16_t)Wq1[i];
        if (bid == POOL2_BLOCKS && tid < 4) acc[tid] = 0.f;
        return;
    }
    int kv = bid >> 12;          // 0 = K, 1 = V
    int e0 = bid & 4095;         // b*512 + c
    int b = e0 >> 9;
    int c = e0 & 511;
    const float* src = kv ? V : K;
    __shared__ float buf[2048];
    const float* base = src + (size_t)e0 * 2048;
    #pragma unroll
    for (int i = 0; i < 2; ++i) {
        int i4 = (tid + i * 256) << 2;
        *(float4*)&buf[i4] = *(const float4*)&base[i4];
    }
    __syncthreads();
    if (tid < LK) {
        int p0 = tid * 9 - 4;
        float mx = -3.4e38f;
        #pragma unroll
        for (int j = 0; j < 9; ++j) {
            int p = p0 + j;
            if (p >= 0 && p < 2048) mx = fmaxf(mx, buf[p]);
        }
        int e = b * KP_PER_B + c * LK + tid;
        if (kv) Vpb[e] = (bf16_t)mx;
        else    Kp[e]  = mx;
    }
}

// ------------- kernel 2: sparse q-MLP, b-specialized unrolled layer 1 --------
// R11-verified state (95us: R5 inner stream + k-loop full unroll, VGPR 44,
// FETCH 3.5MB, zero spill). Single change this round:
//  REVERSED block order (bl = 1823-bid): heavy b=7 blocks launch FIRST, so
//  the dispatch tail is near-free b=0/1 blocks instead of a low-parallelism
//  stretch of 7x-work blocks. Consecutive bids still share b and adjacent l
//  -> Kp L2 locality preserved (unlike the R8 b-interleave which doubled
//  FETCH). Occupancy 33% vs 62.5% LDS cap is ramp/tail -- this shortens it.
// LDS: Sstf f32[7][512] @0 (14336) | hT f32[100][44] @14336 (17600) |
//      stats f32[111] @31936 -> 32384 B (5 blocks/CU HW cap).
template<int B>
__device__ __forceinline__ void layer1(int tid, const bf16_t* __restrict__ W1b,
                                       const float* __restrict__ Sstf,
                                       float* __restrict__ hT) {
    #pragma unroll
    for (int k = 0; k < 2; ++k) {
        int vt = tid + (k << 8);
        if (vt < 500) {
            int m = vt / 5;
            int h8 = vt - m * 5;            // 0..4 -> cols h8*8..h8*8+7
            int bm = (12 * m) % 100;
            float h[8];
            #pragma unroll
            for (int i = 0; i < 8; ++i) h[i] = 0.f;
            #pragma unroll
            for (int s = 1; s <= B; ++s) {
                const int t = 99 - B + s;
                int d0 = t - bm; if (d0 < 0) d0 += 100;
                int r0 = ((m << 9) + d0 - t) / 100;   // exact division
                const float* srow = &Sstf[(s - 1) << 9];
                #pragma unroll
                for (int j = 0; j < 6; ++j) {
                    int c = d0 + j * 100;
                    if (j < 5 || c < 512) {
                        float v = srow[r0 + j];
                        bf16x8 w = *(const bf16x8*)&W1b[c * 40 + h8 * 8];
                        #pragma unroll
                        for (int i = 0; i < 8; ++i)
                            h[i] = fmaf(v, (float)w[i], h[i]);
                    }
                }
            }
            #pragma unroll
            for (int i = 0; i < 8; ++i) hT[m * 44 + h8 * 8 + i] = h[i];
        }
    }
}

__global__ __launch_bounds__(256, 4) void k_mlp(
        const float* __restrict__ Kp, const bf16_t* __restrict__ W1b,
        const float* __restrict__ bq1,
        const float* __restrict__ Wq2, const float* __restrict__ bq2,
        float* __restrict__ mu_g, float* __restrict__ centers_g,
        float* __restrict__ acc_g) {
    __shared__ __align__(16) char smem[32384];
    float* Sstf  = (float*)smem;                 // [7][512], row (bk-1)
    float* hT    = (float*)(smem + 14336);       // [100][44]
    float* stats = (float*)(smem + 31936);       // [0..9]=total [10..109]=S [110]=lp

    int tid = threadIdx.x;
    int bl = 1823 - (int)blockIdx.x;  // REVERSED: heavy b=7 first, light tail
    int b = bl / LK;
    int l = bl % LK;

    // stage Sstf rows for bk=1..b: coalesced float4 copy from Kp
    for (int s4 = tid; s4 < 128 * b; s4 += 256) {
        int bk = (s4 >> 7) + 1;
        int r4 = (s4 & 127) << 2;
        *(float4*)&Sstf[((bk - 1) << 9) + r4] =
            *(const float4*)&Kp[bk * KP_PER_B + l * 512 + r4];
    }
    if (tid < 111) stats[tid] = 0.f;
    if (b == 0) {
        for (int i = tid; i < 4400; i += 256) hT[i] = 0.f;
    }
    __syncthreads();

    switch (b) {
        case 1: layer1<1>(tid, W1b, Sstf, hT); break;
        case 2: layer1<2>(tid, W1b, Sstf, hT); break;
        case 3: layer1<3>(tid, W1b, Sstf, hT); break;
        case 4: layer1<4>(tid, W1b, Sstf, hT); break;
        case 5: layer1<5>(tid, W1b, Sstf, hT); break;
        case 6: layer1<6>(tid, W1b, Sstf, hT); break;
        case 7: layer1<7>(tid, W1b, Sstf, hT); break;
        default: break;
    }
    __syncthreads();

    // gelu(+bias) in place, distributed
    for (int i = tid; i < 4000; i += 256) {
        int row = i / 40;
        int j = i - row * 40;
        hT[row * 44 + j] = gelu_f(hT[row * 44 + j] + bq1[j]);
    }
    __syncthreads();

    float* total_l = stats;
    float* S_l = stats + 10;
    float* lp_acc = stats + 110;

    if (tid < 100) {
        int row = tid;
        float g[40];
        #pragma unroll
        for (int j4 = 0; j4 < 10; ++j4) {
            float4 gv = *(const float4*)&hT[row * 44 + j4 * 4];
            g[j4 * 4 + 0] = gv.x; g[j4 * 4 + 1] = gv.y;
            g[j4 * 4 + 2] = gv.z; g[j4 * 4 + 3] = gv.w;
        }
        float out[10];
        #pragma unroll
        for (int c = 0; c < 10; ++c) out[c] = bq2[c];
        #pragma unroll
        for (int j = 0; j < 40; ++j) {
            float gj = g[j];
            #pragma unroll
            for (int c = 0; c < 10; ++c)
                out[c] = fmaf(gj, Wq2[j * 10 + c], out[c]);
        }
        float m = out[0]; int am = 0;
        #pragma unroll
        for (int c = 1; c < 10; ++c)
            if (out[c] > m) { m = out[c]; am = c; }
        float e[10], s = 0.f;
        #pragma unroll
        for (int c = 0; c < 10; ++c) { e[c] = expf(out[c] - m); s += e[c]; }
        float inv = 1.f / s;
        float cq[10], s1 = 0.f;
        #pragma unroll
        for (int c = 0; c < 10; ++c) { cq[c] = e[c] * inv; s1 += cq[c]; }
        float mean = s1 * 0.1f;
        float var = 0.f;
        #pragma unroll
        for (int c = 0; c < 10; ++c) { float d = cq[c] - mean; var += d * d; }
        float sd = sqrtf(var / 9.f);
        float sp = log1pf(expf(sd));             // softplus(std)
        float lp = -logf(sp) - 0.91893853320467274f;  // ((x-mu)/sigma)^2 ~ 1e-16
        mu_g[bl * 100 + row] = mean;
        atomicAdd(lp_acc, lp);
        #pragma unroll
        for (int c = 0; c < 10; ++c) {
            atomicAdd(&total_l[c], cq[c]);
            atomicAdd(&S_l[am * 10 + c], cq[c]);
        }
    }
    __syncthreads();
    if (tid == 0) atomicAdd(&acc_g[0], lp_acc[0]);
    if (tid < 100) {
        centers_g[bl * 100 + tid] = (total_l[tid % 10] - S_l[tid]) * 0.01f;
    }
}

// ------------- kernel 3: fused [proj_back+reshape-sum] ++ [cross-entropy] ---
// Blocks 0..3647: ccs (bf16 output). Blocks 3648..3847: ce, 4 wave-units per
// block. Shift-only ccs index math (verified R9). ce reads strided mu
// (L2-resident, verified R0-R8).
__global__ void k_ccs_ce(const float* __restrict__ centers_g,
                         const float* __restrict__ Wp, const float* __restrict__ bp,
                         bf16_t* __restrict__ ccs_b,
                         const float* __restrict__ mu_g, float* __restrict__ acc_g,
                         float* __restrict__ outp) {
    int bid = blockIdx.x;
    if (bid < KCCS_BLOCKS) {
        int tid = bid * 256 + threadIdx.x;
        int k2d2 = tid % (LK * DK);
        int bh = tid / (LK * DK);
        float s = 0.f;
        #pragma unroll
        for (int i2 = 0; i2 < 10; ++i2) {
            int J  = bh * 10 + i2;
            int i  = J >> 6;
            int Jm = J & 63;
            int bs = Jm >> 3;
            int r2 = (Jm & 7) * 14592 + k2d2;
            int ls = r2 >> 9;
            int mm = r2 & 511;
            const float* cen = centers_g + (bs * LK + ls) * 100 + i * 10;
            float val = bp[mm];
            #pragma unroll
            for (int c = 0; c < 10; ++c)
                val = fmaf(cen[c], Wp[c * 512 + mm], val);
            s += gelu_f(val);
        }
        ccs_b[tid] = (bf16_t)s;
        return;
    }
    // ---- ce part: unit = (bid-KCCS)*4 + wave ----
    int unit = (bid - KCCS_BLOCKS) * 4 + (threadIdx.x >> 6);
    int b = unit / 100;
    int u = unit % 100;
    int lane = threadIdx.x & 63;
    float v[4];
    #pragma unroll
    for (int t = 0; t < 4; ++t) {
        int l = lane + t * 64;
        v[t] = (l < LK) ? mu_g[(b * LK + l) * 100 + u] : -3.4e38f;
    }
    float m = fmaxf(fmaxf(v[0], v[1]), fmaxf(v[2], v[3]));
    for (int o = 32; o > 0; o >>= 1) m = fmaxf(m, __shfl_xor(m, o, 64));
    float se = 0.f;
    #pragma unroll
    for (int t = 0; t < 4; ++t) {
        int l = lane + t * 64;
        if (l < LK) se += expf(v[t] - m);
    }
    for (int o = 32; o > 0; o >>= 1) se += __shfl_xor(se, o, 64);
    float lse = m + logf(se);
    float dot = 0.f;
    #pragma unroll
    for (int t = 0; t < 4; ++t) {
        int l = lane + t * 64;
        if (l < LK) dot += v[t] * (v[t] - lse);
    }
    for (int o = 32; o > 0; o >>= 1) dot += __shfl_xor(dot, o, 64);
    if (lane == 0) {
        atomicAdd(&acc_g[1], -dot * (1.f / 800.f));
        __threadfence();
        unsigned int old = atomicAdd((unsigned int*)&acc_g[2], 1u);
        if (old == 799u) {
            __threadfence();
            outp[8388608] = -(acc_g[0] * (1.f / (float)NROWS)) + acc_g[1];
        }
    }
}

// ------------- kernel 4: MFMA flash attention (228 keys, chunks of 64) ------
// K (ccs) and V (Vp) arrive as bf16: bf16x4 staging, no cvt. 1/8 scale folded
// into Q staging (power-of-2, exact). launch_bounds (256,4).
#define QT 128
__global__ __launch_bounds__(256, 4) void k_attn(
        const float* __restrict__ Q, const bf16_t* __restrict__ ccs_b,
        const bf16_t* __restrict__ Vpb, float* __restrict__ outp) {
    __shared__ __align__(16) char smem[36864];
    bf16_t* Kl = (bf16_t*)(smem);
    bf16_t* Vt = (bf16_t*)(smem + 9216);
    bf16_t* Pl = (bf16_t*)(smem + 18432);

    int tid = threadIdx.x;
    int wid = tid >> 6;
    int lane = tid & 63;
    int ln = lane & 15;
    int qd = lane >> 4;
    int bid = blockIdx.x;        // 1024
    int bh = bid >> 4;           // b*8+h
    int qt = bid & 15;
    int qbase = qt * QT;

    const float*  Qbh = Q + (size_t)bh * SL * DK;
    const bf16_t* Kbh = ccs_b + (size_t)bh * LK * DK;
    const bf16_t* Vbh = Vpb + (size_t)bh * LK * DK;

    for (int s = tid; s < QT * 32; s += 256) {
        int r = s >> 5;
        int c2 = s & 31;
        float2 v = *(const float2*)&Qbh[(size_t)(qbase + r) * DK + c2 * 2];
        *(bf16x2*)&Pl[r * 72 + c2 * 2] =
            (bf16x2){(bf16_t)(v.x * 0.125f), (bf16_t)(v.y * 0.125f)};
    }
    __syncthreads();
    bf16x8 qf[2][2];
    #pragma unroll
    for (int mt = 0; mt < 2; ++mt)
        #pragma unroll
        for (int ks = 0; ks < 2; ++ks)
            qf[mt][ks] = *(const bf16x8*)&Pl[(wid * 32 + mt * 16 + ln) * 72 + ks * 32 + qd * 8];

    f32x4 acc_o[2][4];
    float mrow[2][4], lrow[2][4];
    #pragma unroll
    for (int mt = 0; mt < 2; ++mt)
        #pragma unroll
        for (int t = 0; t < 4; ++t) {
            acc_o[mt][t] = (f32x4)(0.f);
            mrow[mt][t] = -3.0e38f;
            lrow[mt][t] = 0.f;
        }

    for (int ch = 0; ch < 4; ++ch) {
        int k0 = ch * 64;
        __syncthreads();
        for (int s = tid; s < 64 * 16; s += 256) {
            int kk = s >> 4;
            int c4 = s & 15;
            int key = k0 + kk;
            bf16x4 v = (key < LK) ? *(const bf16x4*)&Kbh[key * DK + c4 * 4]
                                  : (bf16x4)(bf16_t)0.f;
            *(bf16x4*)&Kl[kk * 72 + c4 * 4] = v;
        }
        for (int s = tid; s < 64 * 16; s += 256) {
            int kk = s >> 4;
            int c4 = s & 15;
            int key = k0 + kk;
            bf16x4 v = (key < LK) ? *(const bf16x4*)&Vbh[key * DK + c4 * 4]
                                  : (bf16x4)(bf16_t)0.f;
            Vt[(c4 * 4 + 0) * 72 + kk] = v[0];
            Vt[(c4 * 4 + 1) * 72 + kk] = v[1];
            Vt[(c4 * 4 + 2) * 72 + kk] = v[2];
            Vt[(c4 * 4 + 3) * 72 + kk] = v[3];
        }
        __syncthreads();

        f32x4 accs[2][4];
        #pragma unroll
        for (int mt = 0; mt < 2; ++mt)
            #pragma unroll
            for (int nt = 0; nt < 4; ++nt) accs[mt][nt] = (f32x4)(0.f);
        #pragma unroll
        for (int ks = 0; ks < 2; ++ks) {
            #pragma unroll
            for (int nt = 0; nt < 4; ++nt) {
                bf16x8 bf = *(const bf16x8*)&Kl[(nt * 16 + ln) * 72 + ks * 32 + qd * 8];
                #pragma unroll
                for (int mt = 0; mt < 2; ++mt)
                    accs[mt][nt] = __builtin_amdgcn_mfma_f32_16x16x32_bf16(qf[mt][ks], bf, accs[mt][nt], 0, 0, 0);
            }
        }

        #pragma unroll
        for (int mt = 0; mt < 2; ++mt) {
            #pragma unroll
            for (int r = 0; r < 4; ++r) {
                float sv[4];
                #pragma unroll
                for (int nt = 0; nt < 4; ++nt) {
                    float s = accs[mt][nt][r];
                    int key = k0 + nt * 16 + ln;
                    sv[nt] = (key < LK) ? s : -3.0e38f;
                }
                float rmax = fmaxf(fmaxf(sv[0], sv[1]), fmaxf(sv[2], sv[3]));
                #pragma unroll
                for (int o = 1; o < 16; o <<= 1)
                    rmax = fmaxf(rmax, __shfl_xor(rmax, o, 64));
                float mold = mrow[mt][r];
                float mnew = fmaxf(mold, rmax);
                float alpha = __expf(mold - mnew);
                float p[4], psum = 0.f;
                #pragma unroll
                for (int nt = 0; nt < 4; ++nt) {
                    p[nt] = __expf(sv[nt] - mnew);
                    psum += p[nt];
                }
                #pragma unroll
                for (int o = 1; o < 16; o <<= 1)
                    psum += __shfl_xor(psum, o, 64);
                lrow[mt][r] = lrow[mt][r] * alpha + psum;
                mrow[mt][r] = mnew;
                #pragma unroll
                for (int ntv = 0; ntv < 4; ++ntv)
                    acc_o[mt][ntv][r] *= alpha;
                int prow = (wid * 32 + mt * 16 + qd * 4 + r) * 72;
                #pragma unroll
                for (int nt = 0; nt < 4; ++nt)
                    Pl[prow + nt * 16 + ln] = (bf16_t)p[nt];
            }
        }

        #pragma unroll
        for (int ks = 0; ks < 2; ++ks) {
            bf16x8 pa[2];
            #pragma unroll
            for (int mt = 0; mt < 2; ++mt)
                pa[mt] = *(const bf16x8*)&Pl[(wid * 32 + mt * 16 + ln) * 72 + ks * 32 + qd * 8];
            #pragma unroll
            for (int ntv = 0; ntv < 4; ++ntv) {
                bf16x8 vb = *(const bf16x8*)&Vt[(ntv * 16 + ln) * 72 + ks * 32 + qd * 8];
                #pragma unroll
                for (int mt = 0; mt < 2; ++mt)
                    acc_o[mt][ntv] = __builtin_amdgcn_mfma_f32_16x16x32_bf16(pa[mt], vb, acc_o[mt][ntv], 0, 0, 0);
            }
        }
    }

    #pragma unroll
    for (int mt = 0; mt < 2; ++mt) {
        #pragma unroll
        for (int r = 0; r < 4; ++r) {
            float inv = 1.f / lrow[mt][r];
            int q_idx = qbase + wid * 32 + mt * 16 + qd * 4 + r;
            float* orow = outp + ((size_t)bh * SL + q_idx) * DK;
            #pragma unroll
            for (int ntv = 0; ntv < 4; ++ntv)
                orow[ntv * 16 + ln] = acc_o[mt][ntv][r] * inv;
        }
    }
}

extern "C" void kernel_launch(void* const* d_in, const int* in_sizes, int n_in,
                              void* d_out, int out_size, void* d_ws, size_t ws_size,
                              hipStream_t stream) {
    const float* Q   = (const float*)d_in[0];
    const float* K   = (const float*)d_in[1];
    const float* V   = (const float*)d_in[2];
    const float* Wq1 = (const float*)d_in[7];
    const float* bq1 = (const float*)d_in[8];
    const float* Wq2 = (const float*)d_in[9];
    const float* bq2 = (const float*)d_in[10];
    const float* Wp  = (const float*)d_in[11];
    const float* bp  = (const float*)d_in[12];
    float* out = (float*)d_out;

    float* ws      = (float*)d_ws;
    float* Kp      = ws;                 // 933888 f32
    bf16_t* Vpb    = (bf16_t*)(ws + 933888);   // 933888 bf16
    float* mu      = ws + 1867776;       // 182400
    float* centers = ws + 2050176;       // 182400
    bf16_t* ccsb   = (bf16_t*)(ws + 2232576);  // 933888 bf16
    float* acc     = ws + 3166464;       // 4 (acc[2] doubles as uint counter)
    bf16_t* W1b    = (bf16_t*)(ws + 3166468);  // 512*40 bf16 = 40960 B

    // pool (+ W1 prep + acc init) -> mlp -> [ccs ++ ce(+final)] -> attn
    k_pool<<<POOL2_BLOCKS + 80, 256, 0, stream>>>(K, V, Kp, Vpb, Wq1, W1b, acc);
    k_mlp<<<NB * LK, 256, 0, stream>>>(Kp, W1b, bq1, Wq2, bq2, mu, centers, acc);
    k_ccs_ce<<<KCCS_BLOCKS + KCE_BLOCKS, 256, 0, stream>>>(centers, Wp, bp, ccsb,
                                                           mu, acc, out);
    k_attn<<<NB * NH * (SL / QT), 256, 0, stream>>>(Q, ccsb, Vpb, out);
}

// Round 13
// 320.787 us; speedup vs baseline: 1.0014x; 1.0014x over previous
//
#include <hip/hip_runtime.h>
#include <math.h>

#define NCL 10
#define DM 512
#define NH 8
#define DK 64
#define NB 8
#define SL 2048
#define LK 228
#define UF 100
#define KP_PER_B (NH*LK*DK)     // 116736
#define KP_TOT (NB*KP_PER_B)    // 933888
#define NROWS (NB*LK*UF)        // 182400
#define POOLK_BLOCKS 4096       // NB*DM K-channels, one per block
#define KCCS_BLOCKS 3648        // KP_TOT/256
#define KCE_BLOCKS 200          // 800 (b,u) units, 4 per block

typedef __bf16 bf16_t;
typedef __attribute__((ext_vector_type(2))) __bf16 bf16x2;
typedef __attribute__((ext_vector_type(4))) __bf16 bf16x4;
typedef __attribute__((ext_vector_type(8))) __bf16 bf16x8;
typedef __attribute__((ext_vector_type(4))) float f32x4;

__device__ __forceinline__ float gelu_f(float x) {
    return 0.5f * x * (1.f + erff(x * 0.70710678118654752f));
}

// ------------- kernel 1: max-pool K ONLY (+ W1 bf16 prep, acc init) ----------
// V-pool moved into launch 3 (ccs_ce): Vpb is consumed only by attn, so it is
// NOT a k_mlp dependency -- this halves pool's critical-path contribution.
// One block per (b, c) K-channel; stage 2048-float row via float4, max from
// LDS (stride 9 coprime to 32 banks -> conflict-free).
__global__ void k_pool(const float* __restrict__ K, float* __restrict__ Kp,
                       const float* __restrict__ Wq1, bf16_t* __restrict__ W1b,
                       float* __restrict__ acc) {
    int bid = blockIdx.x;
    int tid = threadIdx.x;
    if (bid >= POOLK_BLOCKS) {
        int i = (bid - POOLK_BLOCKS) * 256 + tid;
        if (i < 512 * 40) W1b[i] = (bf16_t)Wq1[i];
        if (bid == POOLK_BLOCKS && tid < 4) acc[tid] = 0.f;
        return;
    }
    int e0 = bid;                // b*512 + c
    int b = e0 >> 9;
    int c = e0 & 511;
    __shared__ float buf[2048];
    const float* base = K + (size_t)e0 * 2048;
    #pragma unroll
    for (int i = 0; i < 2; ++i) {
        int i4 = (tid + i * 256) << 2;
        *(float4*)&buf[i4] = *(const float4*)&base[i4];
    }
    __syncthreads();
    if (tid < LK) {
        int p0 = tid * 9 - 4;
        float mx = -3.4e38f;
        #pragma unroll
        for (int j = 0; j < 9; ++j) {
            int p = p0 + j;
            if (p >= 0 && p < 2048) mx = fmaxf(mx, buf[p]);
        }
        Kp[b * KP_PER_B + c * LK + tid] = mx;
    }
}

// ------------- kernel 2: sparse q-MLP, b-specialized unrolled layer 1 --------
// FROZEN at the R11-verified state (95us: R5 inner stream + k-loop full
// unroll, ascending block order, VGPR 44, FETCH 3.5MB, zero spill).
// Ordering experiments complete: ascending 95 / b-interleave 103.5 /
// descending 106.5 us -- ascending co-schedules light+heavy blocks
// mid-dispatch and preserves Kp L2 sharing. DO NOT TOUCH.
// LDS: Sstf f32[7][512] @0 (14336) | hT f32[100][44] @14336 (17600) |
//      stats f32[111] @31936 -> 32384 B (5 blocks/CU HW cap).
template<int B>
__device__ __forceinline__ void layer1(int tid, const bf16_t* __restrict__ W1b,
                                       const float* __restrict__ Sstf,
                                       float* __restrict__ hT) {
    #pragma unroll
    for (int k = 0; k < 2; ++k) {
        int vt = tid + (k << 8);
        if (vt < 500) {
            int m = vt / 5;
            int h8 = vt - m * 5;            // 0..4 -> cols h8*8..h8*8+7
            int bm = (12 * m) % 100;
            float h[8];
            #pragma unroll
            for (int i = 0; i < 8; ++i) h[i] = 0.f;
            #pragma unroll
            for (int s = 1; s <= B; ++s) {
                const int t = 99 - B + s;
                int d0 = t - bm; if (d0 < 0) d0 += 100;
                int r0 = ((m << 9) + d0 - t) / 100;   // exact division
                const float* srow = &Sstf[(s - 1) << 9];
                #pragma unroll
                for (int j = 0; j < 6; ++j) {
                    int c = d0 + j * 100;
                    if (j < 5 || c < 512) {
                        float v = srow[r0 + j];
                        bf16x8 w = *(const bf16x8*)&W1b[c * 40 + h8 * 8];
                        #pragma unroll
                        for (int i = 0; i < 8; ++i)
                            h[i] = fmaf(v, (float)w[i], h[i]);
                    }
                }
            }
            #pragma unroll
            for (int i = 0; i < 8; ++i) hT[m * 44 + h8 * 8 + i] = h[i];
        }
    }
}

__global__ __launch_bounds__(256, 4) void k_mlp(
        const float* __restrict__ Kp, const bf16_t* __restrict__ W1b,
        const float* __restrict__ bq1,
        const float* __restrict__ Wq2, const float* __restrict__ bq2,
        float* __restrict__ mu_g, float* __restrict__ centers_g,
        float* __restrict__ acc_g) {
    __shared__ __align__(16) char smem[32384];
    float* Sstf  = (float*)smem;                 // [7][512], row (bk-1)
    float* hT    = (float*)(smem + 14336);       // [100][44]
    float* stats = (float*)(smem + 31936);       // [0..9]=total [10..109]=S [110]=lp

    int tid = threadIdx.x;
    int bl = blockIdx.x;          // 0..1823, ascending (R11-verified)
    int b = bl / LK;
    int l = bl % LK;

    // stage Sstf rows for bk=1..b: coalesced float4 copy from Kp
    for (int s4 = tid; s4 < 128 * b; s4 += 256) {
        int bk = (s4 >> 7) + 1;
        int r4 = (s4 & 127) << 2;
        *(float4*)&Sstf[((bk - 1) << 9) + r4] =
            *(const float4*)&Kp[bk * KP_PER_B + l * 512 + r4];
    }
    if (tid < 111) stats[tid] = 0.f;
    if (b == 0) {
        for (int i = tid; i < 4400; i += 256) hT[i] = 0.f;
    }
    __syncthreads();

    switch (b) {
        case 1: layer1<1>(tid, W1b, Sstf, hT); break;
        case 2: layer1<2>(tid, W1b, Sstf, hT); break;
        case 3: layer1<3>(tid, W1b, Sstf, hT); break;
        case 4: layer1<4>(tid, W1b, Sstf, hT); break;
        case 5: layer1<5>(tid, W1b, Sstf, hT); break;
        case 6: layer1<6>(tid, W1b, Sstf, hT); break;
        case 7: layer1<7>(tid, W1b, Sstf, hT); break;
        default: break;
    }
    __syncthreads();

    // gelu(+bias) in place, distributed
    for (int i = tid; i < 4000; i += 256) {
        int row = i / 40;
        int j = i - row * 40;
        hT[row * 44 + j] = gelu_f(hT[row * 44 + j] + bq1[j]);
    }
    __syncthreads();

    float* total_l = stats;
    float* S_l = stats + 10;
    float* lp_acc = stats + 110;

    if (tid < 100) {
        int row = tid;
        float g[40];
        #pragma unroll
        for (int j4 = 0; j4 < 10; ++j4) {
            float4 gv = *(const float4*)&hT[row * 44 + j4 * 4];
            g[j4 * 4 + 0] = gv.x; g[j4 * 4 + 1] = gv.y;
            g[j4 * 4 + 2] = gv.z; g[j4 * 4 + 3] = gv.w;
        }
        float out[10];
        #pragma unroll
        for (int c = 0; c < 10; ++c) out[c] = bq2[c];
        #pragma unroll
        for (int j = 0; j < 40; ++j) {
            float gj = g[j];
            #pragma unroll
            for (int c = 0; c < 10; ++c)
                out[c] = fmaf(gj, Wq2[j * 10 + c], out[c]);
        }
        float m = out[0]; int am = 0;
        #pragma unroll
        for (int c = 1; c < 10; ++c)
            if (out[c] > m) { m = out[c]; am = c; }
        float e[10], s = 0.f;
        #pragma unroll
        for (int c = 0; c < 10; ++c) { e[c] = expf(out[c] - m); s += e[c]; }
        float inv = 1.f / s;
        float cq[10], s1 = 0.f;
        #pragma unroll
        for (int c = 0; c < 10; ++c) { cq[c] = e[c] * inv; s1 += cq[c]; }
        float mean = s1 * 0.1f;
        float var = 0.f;
        #pragma unroll
        for (int c = 0; c < 10; ++c) { float d = cq[c] - mean; var += d * d; }
        float sd = sqrtf(var / 9.f);
        float sp = log1pf(expf(sd));             // softplus(std)
        float lp = -logf(sp) - 0.91893853320467274f;  // ((x-mu)/sigma)^2 ~ 1e-16
        mu_g[bl * 100 + row] = mean;
        atomicAdd(lp_acc, lp);
        #pragma unroll
        for (int c = 0; c < 10; ++c) {
            atomicAdd(&total_l[c], cq[c]);
            atomicAdd(&S_l[am * 10 + c], cq[c]);
        }
    }
    __syncthreads();
    if (tid == 0) atomicAdd(&acc_g[0], lp_acc[0]);
    if (tid < 100) {
        centers_g[bl * 100 + tid] = (total_l[tid % 10] - S_l[tid]) * 0.01f;
    }
}

// ------------- kernel 3: [V-pool] ++ [proj_back+reshape-sum] ++ [ce] --------
// Blocks 0..4095: V max-pool -> bf16 Vpb (moved here from k_pool; only attn
// consumes Vpb, so overlapping it with ccs/ce shortens the critical path).
// Blocks 4096..7743: ccs (bf16 output, shift-only index math, verified R9).
// Blocks 7744..7943: ce, 4 wave-units per block (strided mu reads, verified).
__global__ void k_vp_ccs_ce(const float* __restrict__ V, bf16_t* __restrict__ Vpb,
                            const float* __restrict__ centers_g,
                            const float* __restrict__ Wp, const float* __restrict__ bp,
                            bf16_t* __restrict__ ccs_b,
                            const float* __restrict__ mu_g, float* __restrict__ acc_g,
                            float* __restrict__ outp) {
    int bid = blockIdx.x;
    int tid = threadIdx.x;
    if (bid < POOLK_BLOCKS) {
        // ---- V-pool (verbatim from the verified pool body) ----
        int e0 = bid;            // b*512 + c
        int b = e0 >> 9;
        int c = e0 & 511;
        __shared__ float buf[2048];
        const float* base = V + (size_t)e0 * 2048;
        #pragma unroll
        for (int i = 0; i < 2; ++i) {
            int i4 = (tid + i * 256) << 2;
            *(float4*)&buf[i4] = *(const float4*)&base[i4];
        }
        __syncthreads();
        if (tid < LK) {
            int p0 = tid * 9 - 4;
            float mx = -3.4e38f;
            #pragma unroll
            for (int j = 0; j < 9; ++j) {
                int p = p0 + j;
                if (p >= 0 && p < 2048) mx = fmaxf(mx, buf[p]);
            }
            Vpb[b * KP_PER_B + c * LK + tid] = (bf16_t)mx;
        }
        return;
    }
    bid -= POOLK_BLOCKS;
    if (bid < KCCS_BLOCKS) {
        int idx = bid * 256 + tid;
        int k2d2 = idx % (LK * DK);
        int bh = idx / (LK * DK);
        float s = 0.f;
        #pragma unroll
        for (int i2 = 0; i2 < 10; ++i2) {
            int J  = bh * 10 + i2;
            int i  = J >> 6;
            int Jm = J & 63;
            int bs = Jm >> 3;
            int r2 = (Jm & 7) * 14592 + k2d2;
            int ls = r2 >> 9;
            int mm = r2 & 511;
            const float* cen = centers_g + (bs * LK + ls) * 100 + i * 10;
            float val = bp[mm];
            #pragma unroll
            for (int c = 0; c < 10; ++c)
                val = fmaf(cen[c], Wp[c * 512 + mm], val);
            s += gelu_f(val);
        }
        ccs_b[idx] = (bf16_t)s;
        return;
    }
    // ---- ce part: unit = (bid-KCCS)*4 + wave ----
    int unit = (bid - KCCS_BLOCKS) * 4 + (tid >> 6);
    int b = unit / 100;
    int u = unit % 100;
    int lane = tid & 63;
    float v[4];
    #pragma unroll
    for (int t = 0; t < 4; ++t) {
        int l = lane + t * 64;
        v[t] = (l < LK) ? mu_g[(b * LK + l) * 100 + u] : -3.4e38f;
    }
    float m = fmaxf(fmaxf(v[0], v[1]), fmaxf(v[2], v[3]));
    for (int o = 32; o > 0; o >>= 1) m = fmaxf(m, __shfl_xor(m, o, 64));
    float se = 0.f;
    #pragma unroll
    for (int t = 0; t < 4; ++t) {
        int l = lane + t * 64;
        if (l < LK) se += expf(v[t] - m);
    }
    for (int o = 32; o > 0; o >>= 1) se += __shfl_xor(se, o, 64);
    float lse = m + logf(se);
    float dot = 0.f;
    #pragma unroll
    for (int t = 0; t < 4; ++t) {
        int l = lane + t * 64;
        if (l < LK) dot += v[t] * (v[t] - lse);
    }
    for (int o = 32; o > 0; o >>= 1) dot += __shfl_xor(dot, o, 64);
    if (lane == 0) {
        atomicAdd(&acc_g[1], -dot * (1.f / 800.f));
        __threadfence();
        unsigned int old = atomicAdd((unsigned int*)&acc_g[2], 1u);
        if (old == 799u) {
            __threadfence();
            outp[8388608] = -(acc_g[0] * (1.f / (float)NROWS)) + acc_g[1];
        }
    }
}

// ------------- kernel 4: MFMA flash attention (228 keys, chunks of 64) ------
// K (ccs) and V (Vp) arrive as bf16: bf16x4 staging, no cvt. 1/8 scale folded
// into Q staging (power-of-2, exact). launch_bounds (256,4).
#define QT 128
__global__ __launch_bounds__(256, 4) void k_attn(
        const float* __restrict__ Q, const bf16_t* __restrict__ ccs_b,
        const bf16_t* __restrict__ Vpb, float* __restrict__ outp) {
    __shared__ __align__(16) char smem[36864];
    bf16_t* Kl = (bf16_t*)(smem);
    bf16_t* Vt = (bf16_t*)(smem + 9216);
    bf16_t* Pl = (bf16_t*)(smem + 18432);

    int tid = threadIdx.x;
    int wid = tid >> 6;
    int lane = tid & 63;
    int ln = lane & 15;
    int qd = lane >> 4;
    int bid = blockIdx.x;        // 1024
    int bh = bid >> 4;           // b*8+h
    int qt = bid & 15;
    int qbase = qt * QT;

    const float*  Qbh = Q + (size_t)bh * SL * DK;
    const bf16_t* Kbh = ccs_b + (size_t)bh * LK * DK;
    const bf16_t* Vbh = Vpb + (size_t)bh * LK * DK;

    for (int s = tid; s < QT * 32; s += 256) {
        int r = s >> 5;
        int c2 = s & 31;
        float2 v = *(const float2*)&Qbh[(size_t)(qbase + r) * DK + c2 * 2];
        *(bf16x2*)&Pl[r * 72 + c2 * 2] =
            (bf16x2){(bf16_t)(v.x * 0.125f), (bf16_t)(v.y * 0.125f)};
    }
    __syncthreads();
    bf16x8 qf[2][2];
    #pragma unroll
    for (int mt = 0; mt < 2; ++mt)
        #pragma unroll
        for (int ks = 0; ks < 2; ++ks)
            qf[mt][ks] = *(const bf16x8*)&Pl[(wid * 32 + mt * 16 + ln) * 72 + ks * 32 + qd * 8];

    f32x4 acc_o[2][4];
    float mrow[2][4], lrow[2][4];
    #pragma unroll
    for (int mt = 0; mt < 2; ++mt)
        #pragma unroll
        for (int t = 0; t < 4; ++t) {
            acc_o[mt][t] = (f32x4)(0.f);
            mrow[mt][t] = -3.0e38f;
            lrow[mt][t] = 0.f;
        }

    for (int ch = 0; ch < 4; ++ch) {
        int k0 = ch * 64;
        __syncthreads();
        for (int s = tid; s < 64 * 16; s += 256) {
            int kk = s >> 4;
            int c4 = s & 15;
            int key = k0 + kk;
            bf16x4 v = (key < LK) ? *(const bf16x4*)&Kbh[key * DK + c4 * 4]
                                  : (bf16x4)(bf16_t)0.f;
            *(bf16x4*)&Kl[kk * 72 + c4 * 4] = v;
        }
        for (int s = tid; s < 64 * 16; s += 256) {
            int kk = s >> 4;
            int c4 = s & 15;
            int key = k0 + kk;
            bf16x4 v = (key < LK) ? *(const bf16x4*)&Vbh[key * DK + c4 * 4]
                                  : (bf16x4)(bf16_t)0.f;
            Vt[(c4 * 4 + 0) * 72 + kk] = v[0];
            Vt[(c4 * 4 + 1) * 72 + kk] = v[1];
            Vt[(c4 * 4 + 2) * 72 + kk] = v[2];
            Vt[(c4 * 4 + 3) * 72 + kk] = v[3];
        }
        __syncthreads();

        f32x4 accs[2][4];
        #pragma unroll
        for (int mt = 0; mt < 2; ++mt)
            #pragma unroll
            for (int nt = 0; nt < 4; ++nt) accs[mt][nt] = (f32x4)(0.f);
        #pragma unroll
        for (int ks = 0; ks < 2; ++ks) {
            #pragma unroll
            for (int nt = 0; nt < 4; ++nt) {
                bf16x8 bf = *(const bf16x8*)&Kl[(nt * 16 + ln) * 72 + ks * 32 + qd * 8];
                #pragma unroll
                for (int mt = 0; mt < 2; ++mt)
                    accs[mt][nt] = __builtin_amdgcn_mfma_f32_16x16x32_bf16(qf[mt][ks], bf, accs[mt][nt], 0, 0, 0);
            }
        }

        #pragma unroll
        for (int mt = 0; mt < 2; ++mt) {
            #pragma unroll
            for (int r = 0; r < 4; ++r) {
                float sv[4];
                #pragma unroll
                for (int nt = 0; nt < 4; ++nt) {
                    float s = accs[mt][nt][r];
                    int key = k0 + nt * 16 + ln;
                    sv[nt] = (key < LK) ? s : -3.0e38f;
                }
                float rmax = fmaxf(fmaxf(sv[0], sv[1]), fmaxf(sv[2], sv[3]));
                #pragma unroll
                for (int o = 1; o < 16; o <<= 1)
                    rmax = fmaxf(rmax, __shfl_xor(rmax, o, 64));
                float mold = mrow[mt][r];
                float mnew = fmaxf(mold, rmax);
                float alpha = __expf(mold - mnew);
                float p[4], psum = 0.f;
                #pragma unroll
                for (int nt = 0; nt < 4; ++nt) {
                    p[nt] = __expf(sv[nt] - mnew);
                    psum += p[nt];
                }
                #pragma unroll
                for (int o = 1; o < 16; o <<= 1)
                    psum += __shfl_xor(psum, o, 64);
                lrow[mt][r] = lrow[mt][r] * alpha + psum;
                mrow[mt][r] = mnew;
                #pragma unroll
                for (int ntv = 0; ntv < 4; ++ntv)
                    acc_o[mt][ntv][r] *= alpha;
                int prow = (wid * 32 + mt * 16 + qd * 4 + r) * 72;
                #pragma unroll
                for (int nt = 0; nt < 4; ++nt)
                    Pl[prow + nt * 16 + ln] = (bf16_t)p[nt];
            }
        }

        #pragma unroll
        for (int ks = 0; ks < 2; ++ks) {
            bf16x8 pa[2];
            #pragma unroll
            for (int mt = 0; mt < 2; ++mt)
                pa[mt] = *(const bf16x8*)&Pl[(wid * 32 + mt * 16 + ln) * 72 + ks * 32 + qd * 8];
            #pragma unroll
            for (int ntv = 0; ntv < 4; ++ntv) {
                bf16x8 vb = *(const bf16x8*)&Vt[(ntv * 16 + ln) * 72 + ks * 32 + qd * 8];
                #pragma unroll
                for (int mt = 0; mt < 2; ++mt)
                    acc_o[mt][ntv] = __builtin_amdgcn_mfma_f32_16x16x32_bf16(pa[mt], vb, acc_o[mt][ntv], 0, 0, 0);
            }
        }
    }

    #pragma unroll
    for (int mt = 0; mt < 2; ++mt) {
        #pragma unroll
        for (int r = 0; r < 4; ++r) {
            float inv = 1.f / lrow[mt][r];
            int q_idx = qbase + wid * 32 + mt * 16 + qd * 4 + r;
            float* orow = outp + ((size_t)bh * SL + q_idx) * DK;
            #pragma unroll
            for (int ntv = 0; ntv < 4; ++ntv)
                orow[ntv * 16 + ln] = acc_o[mt][ntv][r] * inv;
        }
    }
}

extern "C" void kernel_launch(void* const* d_in, const int* in_sizes, int n_in,
                              void* d_out, int out_size, void* d_ws, size_t ws_size,
                              hipStream_t stream) {
    const float* Q   = (const float*)d_in[0];
    const float* K   = (const float*)d_in[1];
    const float* V   = (const float*)d_in[2];
    const float* Wq1 = (const float*)d_in[7];
    const float* bq1 = (const float*)d_in[8];
    const float* Wq2 = (const float*)d_in[9];
    const float* bq2 = (const float*)d_in[10];
    const float* Wp  = (const float*)d_in[11];
    const float* bp  = (const float*)d_in[12];
    float* out = (float*)d_out;

    float* ws      = (float*)d_ws;
    float* Kp      = ws;                 // 933888 f32
    bf16_t* Vpb    = (bf16_t*)(ws + 933888);   // 933888 bf16
    float* mu      = ws + 1867776;       // 182400
    float* centers = ws + 2050176;       // 182400
    bf16_t* ccsb   = (bf16_t*)(ws + 2232576);  // 933888 bf16
    float* acc     = ws + 3166464;       // 4 (acc[2] doubles as uint counter)
    bf16_t* W1b    = (bf16_t*)(ws + 3166468);  // 512*40 bf16 = 40960 B

    // K-pool(+W1 prep) -> mlp -> [V-pool ++ ccs ++ ce(+final)] -> attn
    k_pool<<<POOLK_BLOCKS + 80, 256, 0, stream>>>(K, Kp, Wq1, W1b, acc);
    k_mlp<<<NB * LK, 256, 0, stream>>>(Kp, W1b, bq1, Wq2, bq2, mu, centers, acc);
    k_vp_ccs_ce<<<POOLK_BLOCKS + KCCS_BLOCKS + KCE_BLOCKS, 256, 0, stream>>>(
        V, Vpb, centers, Wp, bp, ccsb, mu, acc, out);
    k_attn<<<NB * NH * (SL / QT), 256, 0, stream>>>(Q, ccsb, Vpb, out);
}